// Round 6
// baseline (627.274 us; speedup 1.0000x reference)
//
#include <hip/hip_runtime.h>
#include <hip/hip_bf16.h>

#define Bn 32
#define Ln 2048
#define Dn 768
#define Hn 512
#define Mn (Bn*Ln)
#define EPSC 1e-5f

// ws float-offset layout (first 128 KB), then byte regions
#define OFF_S1   0        // [512] masked sum(h)
#define OFF_S2   512      // [512] masked sum(h^2)
#define OFF_CNT  2048     // [32] per-batch counts
#define OFF_PH   2304     // [32*512] pooled relu(BN(h)) sums (atomic)
#define OFF_W1T_BYTES  131072   // bf16 W1^T [512][768]
#define OFF_H_BYTES    1048576  // tiled bf16 h buffer, 64 MB

#define BM 64
#define BN2 256
#define BK 64

typedef __attribute__((ext_vector_type(8))) short bf16x8;
typedef __attribute__((ext_vector_type(4))) float f32x4;

static __device__ __forceinline__ unsigned short f2bf(float x) {
  __hip_bfloat16 h = __float2bfloat16(x);
  return *reinterpret_cast<unsigned short*>(&h);
}
static __device__ __forceinline__ unsigned int pk2(float lo, float hi) {
  return (unsigned int)f2bf(lo) | ((unsigned int)f2bf(hi) << 16);
}
static __device__ __forceinline__ float bf2f(unsigned short u) {
  return __uint_as_float(((unsigned int)u) << 16);
}

// blocks 0..31: per-batch valid count. block 32: zero S1,S2,PH.
__global__ __launch_bounds__(256) void pre_kernel(const int* __restrict__ mask,
                                                  float* __restrict__ ws) {
  int blk = blockIdx.x, t = threadIdx.x;
  if (blk < Bn) {
    __shared__ int red[256];
    int s = 0;
#pragma unroll
    for (int i = 0; i < 8; i++) s += mask[blk * Ln + i * 256 + t];
    red[t] = s;
    __syncthreads();
    for (int off = 128; off > 0; off >>= 1) {
      if (t < off) red[t] += red[t + off];
      __syncthreads();
    }
    if (t == 0) ws[OFF_CNT + blk] = (float)red[0];
  } else {
#pragma unroll
    for (int i = 0; i < 4; i++) ws[OFF_S1 + i * 256 + t] = 0.f;
#pragma unroll
    for (int i = 0; i < 64; i++) ws[OFF_PH + i * 256 + t] = 0.f;
  }
}

// W1 [768][512] fp32 -> W1t [512][768] bf16
__global__ __launch_bounds__(256) void transpose_w1(
    const float* __restrict__ W1, unsigned short* __restrict__ W1t) {
  __shared__ float tile[32][33];
  int kx = blockIdx.x * 32;
  int nx = blockIdx.y * 32;
  int tx = threadIdx.x & 31, ty = threadIdx.x >> 5;
#pragma unroll
  for (int i = 0; i < 32; i += 8)
    tile[ty + i][tx] = W1[(size_t)(kx + ty + i) * Hn + nx + tx];
  __syncthreads();
#pragma unroll
  for (int i = 0; i < 32; i += 8)
    W1t[(size_t)(nx + ty + i) * Dn + kx + tx] = f2bf(tile[tx][ty + i]);
}

// GEMM1: h = A @ W1 + b1 via bf16 MFMA, fused masked BN stats.
// Block 64Mx256N, BK=64, 256 thr = 4 waves of 32Mx128N. N-split stays 2
// (bx fastest) so L2/L3 absorb the A re-read (R4 showed 4-split blows FETCH).
// LDS = exactly 40 KB -> 4 blocks/CU, 4 staggered barrier phases, to double
// the HBM issue duty cycle (R5 was 2 phases at 23% HBM).
// LDS rows are unpadded 128 B; 16-B chunks XOR-swizzled: slot = c ^ (row&7)
// -> ds_read_b128 and staging stores at the structural 8-cycle minimum.
// Stats: cross-quad shuffle reduce + direct global atomics (no LDS arrays).
// Hout per 64x256 chunk (chunk = by*2+bx, 16384 elems):
//   w*4096 + (mt*8+nt)*256 + lane*4 + r
__global__ __launch_bounds__(256) void gemm1_mfma(
    const float* __restrict__ A, const unsigned short* __restrict__ W1t,
    const float* __restrict__ b1, const int* __restrict__ mask,
    unsigned short* __restrict__ Hout,
    float* __restrict__ gsum, float* __restrict__ gsq)
{
  __shared__ unsigned short As[BM * BK];   // 8 KB, swizzled
  __shared__ unsigned short Bs[BN2 * BK];  // 32 KB, swizzled

  const int t = threadIdx.x;
  const int bx = blockIdx.x;   // N: 0..1
  const int by = blockIdx.y;   // M: 0..1023
  const int bm0 = by * BM;
  const int bn0 = bx * BN2;

  const int w = t >> 6;
  const int lane = t & 63;
  const int wm0 = (w >> 1) * 32;
  const int wn0 = (w & 1) * 128;
  const int l15 = lane & 15;
  const int quad = lane >> 4;
  const int lsw = l15 & 7;     // frag-read swizzle key

  // A staging: thread -> row t>>2, 16 fp32 at kseg (t&3)*16 -> 2 bf16 chunks
  const int arow = t >> 2;
  const int akc = (t & 3) * 2;
  const float* Ap = A + (size_t)(bm0 + arow) * Dn + akc * 8;
  unsigned short* As0 = &As[arow * 64 + ((akc) ^ (arow & 7)) * 8];
  unsigned short* As1 = &As[arow * 64 + ((akc + 1) ^ (arow & 7)) * 8];

  // B staging: thread -> row t, all 8 chunks
  const unsigned short* Bp = W1t + (size_t)(bn0 + t) * Dn;
  unsigned short* Bsrow = &Bs[t * 64];
  const int bsw = t & 7;

  f32x4 acc[2][8];
#pragma unroll
  for (int i = 0; i < 2; i++)
#pragma unroll
    for (int j = 0; j < 8; j++) acc[i][j] = (f32x4){0.f, 0.f, 0.f, 0.f};

  for (int k0 = 0; k0 < Dn; k0 += BK) {
    float4 a0 = *(const float4*)(Ap + k0);
    float4 a1 = *(const float4*)(Ap + k0 + 4);
    float4 a2 = *(const float4*)(Ap + k0 + 8);
    float4 a3 = *(const float4*)(Ap + k0 + 12);
    uint4 bv[8];
#pragma unroll
    for (int j = 0; j < 8; j++) bv[j] = *(const uint4*)(Bp + k0 + j * 8);
    __syncthreads();
    uint4 p0, p1;
    p0.x = pk2(a0.x, a0.y); p0.y = pk2(a0.z, a0.w);
    p0.z = pk2(a1.x, a1.y); p0.w = pk2(a1.z, a1.w);
    p1.x = pk2(a2.x, a2.y); p1.y = pk2(a2.z, a2.w);
    p1.z = pk2(a3.x, a3.y); p1.w = pk2(a3.z, a3.w);
    *(uint4*)As0 = p0;
    *(uint4*)As1 = p1;
#pragma unroll
    for (int j = 0; j < 8; j++)
      *(uint4*)&Bsrow[(j ^ bsw) * 8] = bv[j];
    __syncthreads();
#pragma unroll
    for (int s = 0; s < 2; s++) {
      const int csw = ((s * 4 + quad) ^ lsw) * 8;
      bf16x8 af[2], bf[8];
#pragma unroll
      for (int mt = 0; mt < 2; mt++)
        af[mt] = *(const bf16x8*)&As[(wm0 + mt * 16 + l15) * 64 + csw];
#pragma unroll
      for (int nt = 0; nt < 8; nt++)
        bf[nt] = *(const bf16x8*)&Bs[(wn0 + nt * 16 + l15) * 64 + csw];
#pragma unroll
      for (int mt = 0; mt < 2; mt++)
#pragma unroll
        for (int nt = 0; nt < 8; nt++)
          acc[mt][nt] = __builtin_amdgcn_mfma_f32_16x16x32_bf16(
              af[mt], bf[nt], acc[mt][nt], 0, 0, 0);
    }
  }

  // ---- epilogue: bias, masked stats (shuffle-reduced), tiled bf16 store ----
  float mk[2][4];
#pragma unroll
  for (int mt = 0; mt < 2; mt++) {
    int4 mv = *(const int4*)(mask + bm0 + wm0 + mt * 16 + quad * 4);
    mk[mt][0] = (float)mv.x; mk[mt][1] = (float)mv.y;
    mk[mt][2] = (float)mv.z; mk[mt][3] = (float)mv.w;
  }

  const size_t cbase = ((size_t)(by * 2 + bx)) * 16384 + (size_t)w * 4096;
#pragma unroll
  for (int nt = 0; nt < 8; nt++) {
    const int nl = wn0 + nt * 16 + l15;
    const float bias = b1[bn0 + nl];
    float ps = 0.f, pq = 0.f;
#pragma unroll
    for (int mt = 0; mt < 2; mt++) {
      ushort4 st;
      float v0 = acc[mt][nt][0] + bias;
      float v1 = acc[mt][nt][1] + bias;
      float v2 = acc[mt][nt][2] + bias;
      float v3 = acc[mt][nt][3] + bias;
      ps += v0 * mk[mt][0] + v1 * mk[mt][1] + v2 * mk[mt][2] + v3 * mk[mt][3];
      pq += v0 * v0 * mk[mt][0] + v1 * v1 * mk[mt][1] +
            v2 * v2 * mk[mt][2] + v3 * v3 * mk[mt][3];
      st.x = f2bf(v0); st.y = f2bf(v1); st.z = f2bf(v2); st.w = f2bf(v3);
      *(ushort4*)&Hout[cbase + (size_t)(mt * 8 + nt) * 256 + lane * 4] = st;
    }
    // reduce across the 4 quads (channel nl is quad-invariant)
    ps += __shfl_xor(ps, 16);
    ps += __shfl_xor(ps, 32);
    pq += __shfl_xor(pq, 16);
    pq += __shfl_xor(pq, 32);
    if (quad == 0) {
      atomicAdd(&gsum[bn0 + nl], ps);
      atomicAdd(&gsq[bn0 + nl], pq);
    }
  }
}

// BN(finalize fused) + ReLU + masked pool over the tiled Hout layout.
// One block per 64x256 chunk (2048 blocks). Thread t owns channel cl=t:
// wlo = t>>7, nt = (t>>4)&7, l15 = t&15; sweeps wm halves h (w = h*2+wlo).
// Register accumulation; one global atomic per channel (32 contenders).
__global__ __launch_bounds__(256) void bnpool_kernel(
    const unsigned short* __restrict__ Hbuf, const int* __restrict__ mask,
    const float* __restrict__ ws, const float* __restrict__ gamma,
    const float* __restrict__ beta, float* __restrict__ PH)
{
  __shared__ float mkf[BM];
  __shared__ float redc[32];
  const int t = threadIdx.x;
  const int chunk = blockIdx.x;        // 0..2047
  const int by = chunk >> 1, bxh = chunk & 1;
  const int b = by >> 5;               // 32 M-chunks per batch
  if (t < 32) redc[t] = ws[OFF_CNT + t];
  if (t < BM) mkf[t] = (float)mask[by * BM + t];
  __syncthreads();

  float nv = 0.f;
#pragma unroll
  for (int i = 0; i < 32; i++) nv += redc[i];
  nv = fmaxf(nv, 1.f);
  const float inv = 1.f / nv;
  const int c = bxh * BN2 + t;
  const float m = ws[OFF_S1 + c] * inv;
  const float var = ws[OFF_S2 + c] * inv - m * m;
  const float istd = rsqrtf(fmaxf(var, 0.f) + EPSC);
  const float scv = istd * gamma[c];
  const float shv = beta[c] - m * scv;

  const int wlo = t >> 7, nt = (t >> 4) & 7, l15 = t & 15;
  float acc = 0.f;
#pragma unroll
  for (int h = 0; h < 2; h++) {
    const int w = h * 2 + wlo;
    const unsigned short* base =
        Hbuf + (size_t)chunk * 16384 + (size_t)w * 4096 + nt * 256 + l15 * 4;
#pragma unroll
    for (int mt = 0; mt < 2; mt++)
#pragma unroll
      for (int q = 0; q < 4; q++) {
        ushort4 hv = *(const ushort4*)(base + mt * 2048 + q * 64);
        const float* mv = &mkf[h * 32 + mt * 16 + q * 4];
        acc += fmaxf(fmaf(bf2f(hv.x), scv, shv), 0.f) * mv[0]
             + fmaxf(fmaf(bf2f(hv.y), scv, shv), 0.f) * mv[1]
             + fmaxf(fmaf(bf2f(hv.z), scv, shv), 0.f) * mv[2]
             + fmaxf(fmaf(bf2f(hv.w), scv, shv), 0.f) * mv[3];
      }
  }
  atomicAdd(&PH[b * Hn + c], acc);
}

// out[b][c] = (PH[b]/max(cnt,1)) @ W2[:,c] + b2[c]*(cnt/max(cnt,1))
__global__ __launch_bounds__(128) void final_kernel(
    const float* __restrict__ pooledh, const float* __restrict__ cnt,
    const float* __restrict__ W2, const float* __restrict__ b2,
    float* __restrict__ out)
{
  __shared__ float pr[Hn];
  int b = blockIdx.x >> 2;
  int cc = blockIdx.x & 3;
  int t = threadIdx.x;
  float nb = cnt[b];
  float inv = 1.f / fmaxf(nb, 1.f);
#pragma unroll
  for (int i = 0; i < 4; i++)
    pr[t + i * 128] = pooledh[b * Hn + t + i * 128] * inv;
  __syncthreads();
  int c = cc * 128 + t;
  float a0 = 0.f, a1 = 0.f, a2 = 0.f, a3 = 0.f;
  for (int i = 0; i < Hn; i += 4) {
    a0 = fmaf(pr[i],     W2[(size_t)i * Hn + c],       a0);
    a1 = fmaf(pr[i + 1], W2[(size_t)(i + 1) * Hn + c], a1);
    a2 = fmaf(pr[i + 2], W2[(size_t)(i + 2) * Hn + c], a2);
    a3 = fmaf(pr[i + 3], W2[(size_t)(i + 3) * Hn + c], a3);
  }
  out[b * Hn + c] = (a0 + a1) + (a2 + a3) + b2[c] * (nb * inv);
}

extern "C" void kernel_launch(void* const* d_in, const int* in_sizes, int n_in,
                              void* d_out, int out_size, void* d_ws, size_t ws_size,
                              hipStream_t stream) {
  const float* hidden = (const float*)d_in[0];
  const int*   mask   = (const int*)d_in[1];
  const float* W1     = (const float*)d_in[2];
  const float* b1     = (const float*)d_in[3];
  const float* gamma  = (const float*)d_in[4];
  const float* beta   = (const float*)d_in[5];
  const float* W2     = (const float*)d_in[6];
  const float* b2     = (const float*)d_in[7];
  float* out = (float*)d_out;
  float* ws  = (float*)d_ws;
  unsigned short* W1t  = (unsigned short*)((char*)d_ws + OFF_W1T_BYTES);
  unsigned short* Hbuf = (unsigned short*)((char*)d_ws + OFF_H_BYTES);

  pre_kernel<<<Bn + 1, 256, 0, stream>>>(mask, ws);
  transpose_w1<<<dim3(Dn / 32, Hn / 32), 256, 0, stream>>>(W1, W1t);
  gemm1_mfma<<<dim3(Hn / BN2, Mn / BM), 256, 0, stream>>>(
      hidden, W1t, b1, mask, Hbuf, ws + OFF_S1, ws + OFF_S2);
  bnpool_kernel<<<(Mn / BM) * (Hn / BN2), 256, 0, stream>>>(
      Hbuf, mask, ws, gamma, beta, ws + OFF_PH);
  final_kernel<<<Bn * 4, 128, 0, stream>>>(ws + OFF_PH, ws + OFF_CNT, W2, b2, out);
}

// Round 7
// 564.949 us; speedup vs baseline: 1.1103x; 1.1103x over previous
//
#include <hip/hip_runtime.h>
#include <hip/hip_bf16.h>

#define Bn 32
#define Ln 2048
#define Dn 768
#define Hn 512
#define Mn (Bn*Ln)
#define EPSC 1e-5f

// ws float-offset layout (first 128 KB), then byte regions
#define OFF_S1   0        // [512] masked sum(h)
#define OFF_S2   512      // [512] masked sum(h^2)
#define OFF_CNT  2048     // [32] per-batch counts
#define OFF_PH   2304     // [32*512] pooled relu(BN(h)) sums (atomic)
#define OFF_W1T_BYTES  131072   // bf16 W1^T [512][768]
#define OFF_H_BYTES    1048576  // tiled bf16 h buffer, 64 MB

#define BM 128
#define BN2 128
#define BK 64

typedef __attribute__((ext_vector_type(8))) short bf16x8;
typedef __attribute__((ext_vector_type(4))) float f32x4;

static __device__ __forceinline__ unsigned short f2bf(float x) {
  __hip_bfloat16 h = __float2bfloat16(x);
  return *reinterpret_cast<unsigned short*>(&h);
}
static __device__ __forceinline__ unsigned int pk2(float lo, float hi) {
  return (unsigned int)f2bf(lo) | ((unsigned int)f2bf(hi) << 16);
}
static __device__ __forceinline__ float bf2f(unsigned short u) {
  return __uint_as_float(((unsigned int)u) << 16);
}

// blocks 0..31: per-batch count; block 32: zero stats; 33..416: W1 transpose.
__global__ __launch_bounds__(256) void prep_kernel(
    const int* __restrict__ mask, const float* __restrict__ W1,
    float* __restrict__ ws, unsigned short* __restrict__ W1t) {
  int blk = blockIdx.x, t = threadIdx.x;
  if (blk < Bn) {
    __shared__ int red[256];
    int s = 0;
#pragma unroll
    for (int i = 0; i < 8; i++) s += mask[blk * Ln + i * 256 + t];
    red[t] = s;
    __syncthreads();
    for (int off = 128; off > 0; off >>= 1) {
      if (t < off) red[t] += red[t + off];
      __syncthreads();
    }
    if (t == 0) ws[OFF_CNT + blk] = (float)red[0];
  } else if (blk == Bn) {
#pragma unroll
    for (int i = 0; i < 4; i++) ws[OFF_S1 + i * 256 + t] = 0.f;
#pragma unroll
    for (int i = 0; i < 64; i++) ws[OFF_PH + i * 256 + t] = 0.f;
  } else {
    __shared__ float tile[32][33];
    int idx = blk - Bn - 1;              // 0..383
    int kx = (idx % 24) * 32;
    int nx = (idx / 24) * 32;
    int tx = t & 31, ty = t >> 5;
#pragma unroll
    for (int i = 0; i < 32; i += 8)
      tile[ty + i][tx] = W1[(size_t)(kx + ty + i) * Hn + nx + tx];
    __syncthreads();
#pragma unroll
    for (int i = 0; i < 32; i += 8)
      W1t[(size_t)(nx + ty + i) * Dn + kx + tx] = f2bf(tile[tx][ty + i]);
  }
}

// GEMM1: h = A @ W1 + b1 via bf16 MFMA, fused masked BN stats.
// Block 128Mx128N, BK=64, 256 thr = 4 waves of 64x64 (2x2). Four independent
// barrier domains per CU (LDS 33.8 KB -> 4 blocks/CU; 64 AGPR + <=64 VGPR ->
// 4 waves/SIMD) to raise the HBM issue duty cycle vs R5's 2 domains.
// Grid (1024,2): x = by*2+b0 keeps same-row N-pairs dispatch-adjacent
// (R5's proven L3 A-sharing; avoids R4's 4-way concurrent A fetch).
// LDS unpadded, 16-B chunks XOR-swizzled slot = c ^ (row&7): R6-proven
// 0 bank conflicts, and saves the pad bytes.
// Stats: LDS csum/csq aggregation -> 256 global atomics per block (0.5M
// total; R6 proved raw per-lane atomics cause a 9x WRITE_SIZE storm).
// Hout per 128x128 chunk (chunk = by*4+bxn, 16384 elems):
//   w*4096 + (mt*4+nt)*256 + lane*4 + r
__global__ __launch_bounds__(256, 4) void gemm1_mfma(
    const float* __restrict__ A, const unsigned short* __restrict__ W1t,
    const float* __restrict__ b1, const int* __restrict__ mask,
    unsigned short* __restrict__ Hout,
    float* __restrict__ gsum, float* __restrict__ gsq)
{
  __shared__ unsigned short As[BM * 64];   // 16 KB, swizzled
  __shared__ unsigned short Bs[BN2 * 64];  // 16 KB, swizzled
  __shared__ float csum[BN2];
  __shared__ float csq[BN2];

  const int t = threadIdx.x;
  const int by = blockIdx.x >> 1;
  const int bxn = blockIdx.y * 2 + (blockIdx.x & 1);  // N-tile 0..3
  const int bm0 = by * BM;
  const int bn0 = bxn * BN2;

  const int w = t >> 6;
  const int lane = t & 63;
  const int wm0 = (w >> 1) * 64;
  const int wn0 = (w & 1) * 64;
  const int l15 = lane & 15;
  const int quad = lane >> 4;

  // staging map: thread covers half a row (32 k's) of A and of B
  const int arow = t >> 1;          // 0..127
  const int kh = t & 1;             // k-half: 0 or 32
  const int c0 = kh * 4;            // first 16-B chunk index
  const int rsw = arow & 7;

  const float* Ap = A + (size_t)(bm0 + arow) * Dn + kh * 32;
  const unsigned short* Bp = W1t + (size_t)(bn0 + arow) * Dn + kh * 32;

  f32x4 acc[4][4];
#pragma unroll
  for (int i = 0; i < 4; i++)
#pragma unroll
    for (int j = 0; j < 4; j++) acc[i][j] = (f32x4){0.f, 0.f, 0.f, 0.f};

  for (int k0 = 0; k0 < Dn; k0 += BK) {
    float4 av[8];
#pragma unroll
    for (int i = 0; i < 8; i++) av[i] = *(const float4*)(Ap + k0 + i * 4);
    uint4 bv[4];
#pragma unroll
    for (int j = 0; j < 4; j++) bv[j] = *(const uint4*)(Bp + k0 + j * 8);
    __syncthreads();
#pragma unroll
    for (int j = 0; j < 4; j++) {
      uint4 pa;
      pa.x = pk2(av[2 * j].x, av[2 * j].y);
      pa.y = pk2(av[2 * j].z, av[2 * j].w);
      pa.z = pk2(av[2 * j + 1].x, av[2 * j + 1].y);
      pa.w = pk2(av[2 * j + 1].z, av[2 * j + 1].w);
      *(uint4*)&As[arow * 64 + ((c0 + j) ^ rsw) * 8] = pa;
      *(uint4*)&Bs[arow * 64 + ((c0 + j) ^ rsw) * 8] = bv[j];
    }
    __syncthreads();
#pragma unroll
    for (int s = 0; s < 2; s++) {
      bf16x8 af[4], bf[4];
#pragma unroll
      for (int mt = 0; mt < 4; mt++) {
        const int r = wm0 + mt * 16 + l15;
        af[mt] = *(const bf16x8*)&As[r * 64 + ((s * 4 + quad) ^ (r & 7)) * 8];
      }
#pragma unroll
      for (int nt = 0; nt < 4; nt++) {
        const int r = wn0 + nt * 16 + l15;
        bf[nt] = *(const bf16x8*)&Bs[r * 64 + ((s * 4 + quad) ^ (r & 7)) * 8];
      }
#pragma unroll
      for (int mt = 0; mt < 4; mt++)
#pragma unroll
        for (int nt = 0; nt < 4; nt++)
          acc[mt][nt] = __builtin_amdgcn_mfma_f32_16x16x32_bf16(
              af[mt], bf[nt], acc[mt][nt], 0, 0, 0);
    }
  }

  // ---- epilogue: bias, masked stats (LDS-aggregated), tiled bf16 store ----
  if (t < BN2) { csum[t] = 0.f; csq[t] = 0.f; }
  __syncthreads();

  float mk[4][4];
#pragma unroll
  for (int mt = 0; mt < 4; mt++) {
    int4 mv = *(const int4*)(mask + bm0 + wm0 + mt * 16 + quad * 4);
    mk[mt][0] = (float)mv.x; mk[mt][1] = (float)mv.y;
    mk[mt][2] = (float)mv.z; mk[mt][3] = (float)mv.w;
  }

  const size_t cbase = ((size_t)(by * 4 + bxn)) * 16384 + (size_t)w * 4096;
#pragma unroll
  for (int nt = 0; nt < 4; nt++) {
    const int nl = wn0 + nt * 16 + l15;
    const float bias = b1[bn0 + nl];
    float ps = 0.f, pq = 0.f;
#pragma unroll
    for (int mt = 0; mt < 4; mt++) {
      ushort4 st;
      float v0 = acc[mt][nt][0] + bias;
      float v1 = acc[mt][nt][1] + bias;
      float v2 = acc[mt][nt][2] + bias;
      float v3 = acc[mt][nt][3] + bias;
      ps += v0 * mk[mt][0] + v1 * mk[mt][1] + v2 * mk[mt][2] + v3 * mk[mt][3];
      pq += v0 * v0 * mk[mt][0] + v1 * v1 * mk[mt][1] +
            v2 * v2 * mk[mt][2] + v3 * v3 * mk[mt][3];
      st.x = f2bf(v0); st.y = f2bf(v1); st.z = f2bf(v2); st.w = f2bf(v3);
      *(ushort4*)&Hout[cbase + (size_t)(mt * 4 + nt) * 256 + lane * 4] = st;
    }
    atomicAdd(&csum[nl], ps);
    atomicAdd(&csq[nl], pq);
  }

  __syncthreads();
  if (t < BN2) {
    atomicAdd(&gsum[bn0 + t], csum[t]);
    atomicAdd(&gsq[bn0 + t], csq[t]);
  }
}

// BN(finalize fused) + ReLU + masked pool over the tiled Hout layout.
// One block per 128x128 chunk (2048 blocks). R4-proven tail.
__global__ __launch_bounds__(256) void bnpool_kernel(
    const unsigned short* __restrict__ Hbuf, const int* __restrict__ mask,
    const float* __restrict__ ws, const float* __restrict__ gamma,
    const float* __restrict__ beta, float* __restrict__ PH)
{
  __shared__ float mkf[BM];
  __shared__ float scs[BN2], shs[BN2];
  __shared__ float part[4][64];
  __shared__ float redc[32];
  const int t = threadIdx.x;
  const int chunk = blockIdx.x;        // 0..2047
  const int by = chunk >> 2, bx = chunk & 3;
  const int b = by >> 4;               // 16 M-chunks per batch
  if (t < 32) redc[t] = ws[OFF_CNT + t];
  if (t < BM) mkf[t] = (float)mask[by * BM + t];
  __syncthreads();
  if (t < BN2) {
    float nv = 0.f;
#pragma unroll
    for (int i = 0; i < 32; i++) nv += redc[i];
    nv = fmaxf(nv, 1.f);
    float inv = 1.f / nv;
    int c = bx * BN2 + t;
    float m = ws[OFF_S1 + c] * inv;
    float var = ws[OFF_S2 + c] * inv - m * m;
    float istd = rsqrtf(fmaxf(var, 0.f) + EPSC);
    float sc = istd * gamma[c];
    scs[t] = sc;
    shs[t] = beta[c] - m * sc;
  }
  __syncthreads();

  const int l15 = t & 15, nt = (t >> 4) & 3, w = t >> 6;
  const int wn0 = (w & 1) * 64, wm0 = (w >> 1) * 64;
  const int nl = wn0 + nt * 16 + l15;
  const float scv = scs[nl], shv = shs[nl];
  const unsigned short* base =
      Hbuf + (size_t)chunk * 16384 + (size_t)w * 4096 + nt * 256 + l15 * 4;
  float acc = 0.f;
#pragma unroll
  for (int mt = 0; mt < 4; mt++)
#pragma unroll
    for (int q = 0; q < 4; q++) {
      ushort4 hv = *(const ushort4*)(base + mt * 1024 + q * 64);
      const float* mv = &mkf[wm0 + mt * 16 + q * 4];
      acc += fmaxf(fmaf(bf2f(hv.x), scv, shv), 0.f) * mv[0]
           + fmaxf(fmaf(bf2f(hv.y), scv, shv), 0.f) * mv[1]
           + fmaxf(fmaf(bf2f(hv.z), scv, shv), 0.f) * mv[2]
           + fmaxf(fmaf(bf2f(hv.w), scv, shv), 0.f) * mv[3];
    }
  part[w][nt * 16 + l15] = acc;
  __syncthreads();
  if (t < BN2) {
    int half = t >> 6, cl = t & 63;
    float v = part[half][cl] + part[half + 2][cl];
    atomicAdd(&PH[b * Hn + bx * BN2 + t], v);
  }
}

// out[b][c] = (PH[b]/max(cnt,1)) @ W2[:,c] + b2[c]*(cnt/max(cnt,1))
__global__ __launch_bounds__(128) void final_kernel(
    const float* __restrict__ pooledh, const float* __restrict__ cnt,
    const float* __restrict__ W2, const float* __restrict__ b2,
    float* __restrict__ out)
{
  __shared__ float pr[Hn];
  int b = blockIdx.x >> 2;
  int cc = blockIdx.x & 3;
  int t = threadIdx.x;
  float nb = cnt[b];
  float inv = 1.f / fmaxf(nb, 1.f);
#pragma unroll
  for (int i = 0; i < 4; i++)
    pr[t + i * 128] = pooledh[b * Hn + t + i * 128] * inv;
  __syncthreads();
  int c = cc * 128 + t;
  float a0 = 0.f, a1 = 0.f, a2 = 0.f, a3 = 0.f;
  for (int i = 0; i < Hn; i += 4) {
    a0 = fmaf(pr[i],     W2[(size_t)i * Hn + c],       a0);
    a1 = fmaf(pr[i + 1], W2[(size_t)(i + 1) * Hn + c], a1);
    a2 = fmaf(pr[i + 2], W2[(size_t)(i + 2) * Hn + c], a2);
    a3 = fmaf(pr[i + 3], W2[(size_t)(i + 3) * Hn + c], a3);
  }
  out[b * Hn + c] = (a0 + a1) + (a2 + a3) + b2[c] * (nb * inv);
}

extern "C" void kernel_launch(void* const* d_in, const int* in_sizes, int n_in,
                              void* d_out, int out_size, void* d_ws, size_t ws_size,
                              hipStream_t stream) {
  const float* hidden = (const float*)d_in[0];
  const int*   mask   = (const int*)d_in[1];
  const float* W1     = (const float*)d_in[2];
  const float* b1     = (const float*)d_in[3];
  const float* gamma  = (const float*)d_in[4];
  const float* beta   = (const float*)d_in[5];
  const float* W2     = (const float*)d_in[6];
  const float* b2     = (const float*)d_in[7];
  float* out = (float*)d_out;
  float* ws  = (float*)d_ws;
  unsigned short* W1t  = (unsigned short*)((char*)d_ws + OFF_W1T_BYTES);
  unsigned short* Hbuf = (unsigned short*)((char*)d_ws + OFF_H_BYTES);

  prep_kernel<<<Bn + 1 + 384, 256, 0, stream>>>(mask, W1, ws, W1t);
  gemm1_mfma<<<dim3(1024, 2), 256, 0, stream>>>(
      hidden, W1t, b1, mask, Hbuf, ws + OFF_S1, ws + OFF_S2);
  bnpool_kernel<<<2048, 256, 0, stream>>>(
      Hbuf, mask, ws, gamma, beta, ws + OFF_PH);
  final_kernel<<<Bn * 4, 128, 0, stream>>>(ws + OFF_PH, ws + OFF_CNT, W2, b2, out);
}